// Round 10
// baseline (319.601 us; speedup 1.0000x reference)
//
#include <hip/hip_runtime.h>

#define N_P 1024
#define N_K 16
#define C_IN 18

typedef _Float16 f16;
typedef f16 f16x8 __attribute__((ext_vector_type(8)));
typedef f16 f16x4 __attribute__((ext_vector_type(4)));
typedef float f32x4 __attribute__((ext_vector_type(4)));

// ---------------------------------------------------------------------------
// Fused EdgeConv. Round-10: two-pass kNN (f32 tau-pass + exact collect pass).
//  Pass 1: per-thread top-17 cascade on RAW f32 d (fminf/fmaxf, full rate;
//          numeric order over finite floats == reference d order). Merge via
//          senders-INF shfl tree (f32). tau = exact 17th-smallest d (incl
//          self, duplicates counted); broadcast to the query's 4 seg-lanes.
//  Pass 2: rescan with bit-identical d; collect d <= tau into per-query LDS
//          lists as f64-packed (mono(d)<<10|idx) keys (atomic slot, cap 25;
//          ties at tau are INCLUDED so the exact (d,idx) top-17 survives).
//  Final:  owner lanes run the verified f64 cascade over ~17 items ->
//          exact top-17 by (d,idx); kk[0] = self dropped.
//  MLP phase unchanged (verified absmax 0.0625 since round 3).
// LDS layout (30224 B):
//  [0,16640)        spts float4[1024]  -> later fbuf[64][65]
//  [16640,29440)    items double[64][25]   (phase B only)
//    aliased after barrier by: hb[4][16][72] @16640 (9216) +
//                              idx_lds[64][16] @25856 (4096)
//  [29952,30208)    cnt int[64]
//  [30208,30224)    msum
// Barrier discipline: B2 writes items -> bar -> B3 reads items into regs ->
// bar -> B4 writes idx_lds / MLP writes hb (items dead). launch_bounds(256,3)
// (round-8/9 lesson: ",4" clamps VGPR to 64 and spills kk[] to scratch).
// ---------------------------------------------------------------------------
__global__ __launch_bounds__(256, 3) void fused_kernel(
    const float* __restrict__ feat, const unsigned char* __restrict__ mask,
    const float* __restrict__ W0, const float* __restrict__ W1,
    const float* __restrict__ W2, const float* __restrict__ Ws,
    const float* __restrict__ g0, const float* __restrict__ b0,
    const float* __restrict__ m0, const float* __restrict__ v0,
    const float* __restrict__ g1, const float* __restrict__ b1,
    const float* __restrict__ m1, const float* __restrict__ v1,
    const float* __restrict__ g2, const float* __restrict__ b2,
    const float* __restrict__ m2, const float* __restrict__ v2,
    const float* __restrict__ gs, const float* __restrict__ bs,
    const float* __restrict__ ms, const float* __restrict__ vs,
    float* __restrict__ out) {

    __shared__ __align__(16) char sbytes[30224];
    float4* spts = (float4*)sbytes;                           // [1024]
    float (*fbuf)[65] = (float(*)[65])sbytes;                 // aliases spts
    double (*items)[25] = (double(*)[25])(sbytes + 16640);    // [64][25], B only
    f16 (*hb)[16][72] = (f16(*)[16][72])(sbytes + 16640);     // aliases items
    int (*idx_lds)[16] = (int(*)[16])(sbytes + 16640 + 9216); // aliases items
    int* cnt = (int*)(sbytes + 29952);                        // [64]
    int* msum = (int*)(sbytes + 30208);

    const int tid = threadIdx.x;
    const int lane = tid & 63;
    const int w = tid >> 6;
    const int g = lane >> 4;
    const int c15 = lane & 15;
    const int n = blockIdx.x >> 4;
    const int P0 = (blockIdx.x & 15) << 6;   // this block's 64 points
    const int PB = P0 + (w << 4);            // this wave's 16 points

    const float* fB = feat + (size_t)n * N_P * C_IN;

    // ---- phase A: stage (x, y, r); zero counters; count mask ----
    if (tid == 0) *msum = 0;
    if (tid < 64) cnt[tid] = 0;
    __syncthreads();
    for (int i = tid; i < N_P; i += 256) {
        float x = fB[i * C_IN + 0];
        float y = fB[i * C_IN + 1];
        float r = __fadd_rn(__fmul_rn(x, x), __fmul_rn(y, y));
        spts[i] = make_float4(x, y, r, 0.f);
    }
    {
        unsigned int m4 = *(const unsigned int*)(mask + (size_t)n * N_P + tid * 4);
        int mc = (int)(((m4 & 0xFFu) != 0) + (((m4 >> 8) & 0xFFu) != 0) +
                       (((m4 >> 16) & 0xFFu) != 0) + (((m4 >> 24) & 0xFFu) != 0));
        atomicAdd(msum, mc);
    }
    __syncthreads();
    const int valid = N_P - *msum;

    const int qid = c15;                 // wave-local query 0..15
    const int qrow = (w << 4) + qid;     // block-local query 0..63
    const int base = g << 8;             // this lane's segment start

    float px, py, rp;
    {
        const float4 me = spts[P0 + qrow];
        px = me.x; py = me.y; rp = me.z;
    }

    // ---- phase B1: f32 d-only cascade + merge -> tau (exact 17th d) ----
    float tau;
    {
        float kd[17];
#pragma unroll
        for (int j = 0; j < 17; ++j) kd[j] = __builtin_inff();

        int off = (2 * g) & 255;             // bank-skewed start
        float4 nq = spts[base + off];
        for (int i = 0; i < 256; ++i) {
            const float4 qc = nq;
            off = (off + 1) & 255;
            nq = spts[base + off];           // broadcast prefetch
            float dot = __fadd_rn(__fmul_rn(px, qc.x), __fmul_rn(py, qc.y));
            float d   = __fadd_rn(__builtin_fmaf(-2.f, dot, rp), qc.z);
            float x = d;
            // branchless sorted-ascending cascade (full-rate f32 min/max)
#pragma unroll
            for (int j = 0; j < 17; ++j) {
                float lo = fminf(kd[j], x);
                x = fmaxf(kd[j], x);
                kd[j] = lo;
            }
        }
        // merge: xor 32 then 16; senders insert +INF (exact no-op)
#pragma unroll
        for (int r = 0; r < 2; ++r) {
            const int m = (r == 0) ? 32 : 16;
            const bool recv = (lane & m) == 0;
#pragma unroll
            for (int j = 0; j < 17; ++j) {
                float x = __shfl_xor(kd[j], m, 64);
                x = recv ? x : __builtin_inff();
#pragma unroll
                for (int jj = 0; jj < 17; ++jj) {
                    float lo = fminf(kd[jj], x);
                    x = fmaxf(kd[jj], x);
                    kd[jj] = lo;
                }
            }
        }
        tau = __shfl(kd[16], c15);   // owner lane qid holds final 17th d
    }

    // ---- phase B2: collect hits (d <= tau) as f64-packed (d,idx) keys ----
    {
        int off = (2 * g) & 255;
        float4 nq = spts[base + off];
        for (int i = 0; i < 256; ++i) {
            const float4 qc = nq;
            const int cur = base + off;
            off = (off + 1) & 255;
            nq = spts[base + off];
            float dot = __fadd_rn(__fmul_rn(px, qc.x), __fmul_rn(py, qc.y));
            float d   = __fadd_rn(__builtin_fmaf(-2.f, dot, rp), qc.z);
            if (d <= tau) {
                unsigned int ud = __float_as_uint(d);
                ud ^= (unsigned int)((int)ud >> 31) | 0x80000000u;  // monotone
                double key = __builtin_fma((double)ud, 1024.0, (double)cur);
                int slot = atomicAdd(&cnt[qrow], 1);
                if (slot < 25) items[qrow][slot] = key;
            }
        }
    }
    __syncthreads();   // items/cnt complete

    // ---- phase B3: owner lanes: exact f64 cascade over collected items ----
    double kk[17];
#pragma unroll
    for (int j = 0; j < 17; ++j) kk[j] = 0x1.0p60;
    if (lane < 16) {
        const int c = min(cnt[qrow], 25);
        for (int j = 0; j < c; ++j) {
            double x = items[qrow][j];
#pragma unroll
            for (int jj = 0; jj < 17; ++jj) {
                double lo = fmin(kk[jj], x);
                x = fmax(kk[jj], x);
                kk[jj] = lo;
            }
        }
    }
    __syncthreads();   // all items reads done; items region dead

    // ---- phase B4: write neighbor indices (kk[0] = self, dropped) ----
    if (lane < 16) {
#pragma unroll
        for (int j = 1; j < 17; ++j) {
            double hi = __builtin_trunc(kk[j] * 0x1.0p-10);
            idx_lds[qrow][j - 1] = (int)(kk[j] - hi * 1024.0);
        }
    }
    // idx_lds rows [16w,16w+16) written and read by the SAME wave: no barrier.

    // ---- fold BN into weight fragments (per-lane registers) ----
    float tb0[4], tb1[4], tb2[4], tbs[4];
    f16x8 w0f[4], w1f[4][2], w2f[4][2];
    f16x4 wsf[4];
#pragma unroll
    for (int t = 0; t < 4; ++t) {
        const int o = t * 16 + c15;
        float s0 = g0[o] / sqrtf(v0[o] + 1e-5f);  tb0[t] = b0[o] - m0[o] * s0;
        float s1 = g1[o] / sqrtf(v1[o] + 1e-5f);  tb1[t] = b1[o] - m1[o] * s1;
        float s2 = g2[o] / sqrtf(v2[o] + 1e-5f);  tb2[t] = b2[o] - m2[o] * s2;
        float ss = gs[o] / sqrtf(vs[o] + 1e-5f);  tbs[t] = bs[o] - ms[o] * ss;
        const float* w0r = W0 + o * 32 + g * 8;
#pragma unroll
        for (int e = 0; e < 8; ++e) w0f[t][e] = (f16)(w0r[e] * s0);
        const float* w1r = W1 + o * 64 + g * 8;
        const float* w2r = W2 + o * 64 + g * 8;
#pragma unroll
        for (int ch = 0; ch < 2; ++ch)
#pragma unroll
            for (int e = 0; e < 8; ++e) {
                w1f[t][ch][e] = (f16)(w1r[ch * 32 + e] * s1);
                w2f[t][ch][e] = (f16)(w2r[ch * 32 + e] * s2);
            }
        const float* wsr = Ws + o * 16 + g * 4;
#pragma unroll
        for (int e = 0; e < 4; ++e) wsf[t][e] = (f16)(wsr[e] * ss);
    }

    // ---- per-point MLP: rows = 16 neighbors, cols = 64 channels ----
    for (int pp = 0; pp < 16; ++pp) {
        const int p = PB + pp;
        const int* ip = idx_lds[(w << 4) + pp];

        const int q = ip[c15];
        const int half = g & 1;
        const float* fcp = fB + p * C_IN + 2 + half * 8;
        float e0[8];
#pragma unroll
        for (int j = 0; j < 4; ++j) {
            float2 v = *(const float2*)(fcp + 2 * j);
            e0[2 * j] = v.x; e0[2 * j + 1] = v.y;
        }
        if (g >= 2) {
            const float* fqp = fB + q * C_IN + 2 + half * 8;
#pragma unroll
            for (int j = 0; j < 4; ++j) {
                float2 v = *(const float2*)(fqp + 2 * j);
                e0[2 * j] -= v.x; e0[2 * j + 1] -= v.y;
            }
        }
        f16x8 a0;
#pragma unroll
        for (int j = 0; j < 8; ++j) a0[j] = (f16)e0[j];

        // layer 0 (K=32), folded-BN bias in acc init
        f32x4 acc[4];
#pragma unroll
        for (int t = 0; t < 4; ++t) {
            acc[t] = (f32x4){tb0[t], tb0[t], tb0[t], tb0[t]};
            acc[t] = __builtin_amdgcn_mfma_f32_16x16x32_f16(a0, w0f[t], acc[t], 0, 0, 0);
        }
#pragma unroll
        for (int t = 0; t < 4; ++t)
#pragma unroll
            for (int r = 0; r < 4; ++r)
                hb[w][4 * g + r][t * 16 + c15] = (f16)fmaxf(acc[t][r], 0.f);

        // layer 1 (K=64)
        f16x8 a1a = *(const f16x8*)&hb[w][c15][g * 8];
        f16x8 a1b = *(const f16x8*)&hb[w][c15][32 + g * 8];
        f32x4 acc1[4];
#pragma unroll
        for (int t = 0; t < 4; ++t) {
            acc1[t] = (f32x4){tb1[t], tb1[t], tb1[t], tb1[t]};
            acc1[t] = __builtin_amdgcn_mfma_f32_16x16x32_f16(a1a, w1f[t][0], acc1[t], 0, 0, 0);
            acc1[t] = __builtin_amdgcn_mfma_f32_16x16x32_f16(a1b, w1f[t][1], acc1[t], 0, 0, 0);
        }
#pragma unroll
        for (int t = 0; t < 4; ++t)
#pragma unroll
            for (int r = 0; r < 4; ++r)
                hb[w][4 * g + r][t * 16 + c15] = (f16)fmaxf(acc1[t][r], 0.f);

        // layer 2 (K=64) + neighbor mask + k-mean
        f16x8 a2a = *(const f16x8*)&hb[w][c15][g * 8];
        f16x8 a2b = *(const f16x8*)&hb[w][c15][32 + g * 8];
        f32x4 acc2[4];
#pragma unroll
        for (int t = 0; t < 4; ++t) {
            acc2[t] = (f32x4){tb2[t], tb2[t], tb2[t], tb2[t]};
            acc2[t] = __builtin_amdgcn_mfma_f32_16x16x32_f16(a2a, w2f[t][0], acc2[t], 0, 0, 0);
            acc2[t] = __builtin_amdgcn_mfma_f32_16x16x32_f16(a2b, w2f[t][1], acc2[t], 0, 0, 0);
        }
        float ssum[4] = {0.f, 0.f, 0.f, 0.f};
        int cnt2 = 0;
#pragma unroll
        for (int r = 0; r < 4; ++r) {
            int qq = ip[4 * g + r];
            bool fl = (qq >= valid);
            cnt2 += fl ? 1 : 0;
#pragma unroll
            for (int t = 0; t < 4; ++t) {
                float v = fmaxf(acc2[t][r], 0.f);
                ssum[t] += fl ? 0.f : v;
            }
        }
#pragma unroll
        for (int t = 0; t < 4; ++t) {
            ssum[t] += __shfl_xor(ssum[t], 16);
            ssum[t] += __shfl_xor(ssum[t], 32);
        }
        cnt2 += __shfl_xor(cnt2, 16);
        cnt2 += __shfl_xor(cnt2, 32);
        float dn = fmaxf((float)(N_K - cnt2), 1e-8f);
        if (g == 0) {
            int prow = (w << 4) + pp;
#pragma unroll
            for (int t = 0; t < 4; ++t)
                fbuf[prow][t * 16 + c15] = ssum[t] / dn;
        }
    }

    // ---- shortcut: sc = BN(Ws @ X) via 16x16x16 MFMA, rows = wave's 16 p ----
    {
        const float* xr = fB + (size_t)(PB + c15) * C_IN + 2 + g * 4;
        float2 xa = *(const float2*)(xr);
        float2 xb = *(const float2*)(xr + 2);
        f16x4 as;
        as[0] = (f16)xa.x; as[1] = (f16)xa.y; as[2] = (f16)xb.x; as[3] = (f16)xb.y;
        f32x4 sacc[4];
#pragma unroll
        for (int t = 0; t < 4; ++t) {
            sacc[t] = (f32x4){tbs[t], tbs[t], tbs[t], tbs[t]};
            sacc[t] = __builtin_amdgcn_mfma_f32_16x16x16f16(as, wsf[t], sacc[t], 0, 0, 0);
        }
        const unsigned char* mrow = mask + (size_t)n * N_P + P0;
#pragma unroll
        for (int r = 0; r < 4; ++r) {
            int pl = (w << 4) + 4 * g + r;
            bool mk = (mrow[pl] != 0);
#pragma unroll
            for (int t = 0; t < 4; ++t) {
                float a = fbuf[pl][t * 16 + c15];
                float sv = mk ? 0.f : sacc[t][r];
                fbuf[pl][t * 16 + c15] = fmaxf(a + sv, 0.f);
            }
        }
    }
    __syncthreads();

    // ---- transposed store: out[n][o][p], coalesced 256B per wave ----
    float* ob = out + (size_t)n * 64 * N_P + P0;
#pragma unroll
    for (int oo = 0; oo < 16; ++oo) {
        int o = (w << 4) + oo;
        ob[(size_t)o * N_P + lane] = fbuf[lane][o];
    }
}

extern "C" void kernel_launch(void* const* d_in, const int* in_sizes, int n_in,
                              void* d_out, int out_size, void* d_ws, size_t ws_size,
                              hipStream_t stream) {
    (void)in_sizes; (void)n_in; (void)out_size; (void)d_ws; (void)ws_size;
    const float* feat = (const float*)d_in[0];
    const unsigned char* mask = (const unsigned char*)d_in[1];
    const float* W0 = (const float*)d_in[2];
    const float* W1 = (const float*)d_in[3];
    const float* W2 = (const float*)d_in[4];
    const float* Ws = (const float*)d_in[5];
    const float* g0 = (const float*)d_in[6];
    const float* b0 = (const float*)d_in[7];
    const float* m0 = (const float*)d_in[8];
    const float* v0 = (const float*)d_in[9];
    const float* g1 = (const float*)d_in[10];
    const float* b1 = (const float*)d_in[11];
    const float* m1 = (const float*)d_in[12];
    const float* v1 = (const float*)d_in[13];
    const float* g2 = (const float*)d_in[14];
    const float* b2 = (const float*)d_in[15];
    const float* m2 = (const float*)d_in[16];
    const float* v2 = (const float*)d_in[17];
    const float* gs = (const float*)d_in[18];
    const float* bs = (const float*)d_in[19];
    const float* ms = (const float*)d_in[20];
    const float* vs = (const float*)d_in[21];
    float* out = (float*)d_out;

    fused_kernel<<<1024, 256, 0, stream>>>(feat, mask, W0, W1, W2, Ws,
                                           g0, b0, m0, v0, g1, b1, m1, v1,
                                           g2, b2, m2, v2, gs, bs, ms, vs,
                                           out);
}

// Round 11
// 290.643 us; speedup vs baseline: 1.0996x; 1.0996x over previous
//
#include <hip/hip_runtime.h>

#define N_P 1024
#define N_K 16
#define C_IN 18

typedef _Float16 f16;
typedef f16 f16x8 __attribute__((ext_vector_type(8)));
typedef f16 f16x4 __attribute__((ext_vector_type(4)));
typedef float f32x4 __attribute__((ext_vector_type(4)));

// ---------------------------------------------------------------------------
// Fused EdgeConv. Round-11: round-9 single-pass f64 kNN with POSITION-WISE
// stable insert (dependency chain 34 -> 2).
//   serial cascade (old): x flows through all 17 positions (34-op chain).
//   position-wise (new):  kk[j] = min(kk[j], max(kk[j-1], x)) descending j,
//                         kk[0] = min(kk[0], x).
//   All max ops read OLD values -> independent; same for mins. For distinct
//   f64 integer keys this is bit-identical to the serial cascade result.
// Merge keeps senders-INF trick: min(kk[j], max(kk[j-1], INF)) == kk[j].
// Round-10 lesson: two-pass collect regressed (wave-level divergent hit block
// fired ~every iter); single-pass f64 is the right structure.
// launch_bounds(256,3): ",4" clamps VGPR to 64 and spills kk[] (round-8).
// MLP phase unchanged (verified absmax 0.0625 since round 3).
// LDS: spts[1024]f4 (16384) aliased by fbuf[64][65] (16640), hb 9216,
//      idx_lds 4096 -> 29968 B total.
// ---------------------------------------------------------------------------
__global__ __launch_bounds__(256, 3) void fused_kernel(
    const float* __restrict__ feat, const unsigned char* __restrict__ mask,
    const float* __restrict__ W0, const float* __restrict__ W1,
    const float* __restrict__ W2, const float* __restrict__ Ws,
    const float* __restrict__ g0, const float* __restrict__ b0,
    const float* __restrict__ m0, const float* __restrict__ v0,
    const float* __restrict__ g1, const float* __restrict__ b1,
    const float* __restrict__ m1, const float* __restrict__ v1,
    const float* __restrict__ g2, const float* __restrict__ b2,
    const float* __restrict__ m2, const float* __restrict__ v2,
    const float* __restrict__ gs, const float* __restrict__ bs,
    const float* __restrict__ ms, const float* __restrict__ vs,
    float* __restrict__ out) {

    __shared__ __align__(16) char sbytes[16640 + 9216 + 4096 + 16];
    float4* spts = (float4*)sbytes;                          // [1024]
    float (*fbuf)[65] = (float(*)[65])sbytes;                // aliases spts
    f16 (*hb)[16][72] = (f16(*)[16][72])(sbytes + 16640);    // [4][16][72]
    int (*idx_lds)[16] = (int(*)[16])(sbytes + 16640 + 9216);// [64][16]
    int* msum = (int*)(sbytes + 16640 + 9216 + 4096);

    const int tid = threadIdx.x;
    const int lane = tid & 63;
    const int w = tid >> 6;
    const int g = lane >> 4;
    const int c15 = lane & 15;
    const int n = blockIdx.x >> 4;
    const int P0 = (blockIdx.x & 15) << 6;   // this block's 64 points
    const int PB = P0 + (w << 4);            // this wave's 16 points

    const float* fB = feat + (size_t)n * N_P * C_IN;

    // ---- phase A: stage (x, y, r); count mask ----
    if (tid == 0) *msum = 0;
    __syncthreads();
    for (int i = tid; i < N_P; i += 256) {
        float x = fB[i * C_IN + 0];
        float y = fB[i * C_IN + 1];
        float r = __fadd_rn(__fmul_rn(x, x), __fmul_rn(y, y));
        spts[i] = make_float4(x, y, r, 0.f);
    }
    {
        unsigned int m4 = *(const unsigned int*)(mask + (size_t)n * N_P + tid * 4);
        int mc = (int)(((m4 & 0xFFu) != 0) + (((m4 >> 8) & 0xFFu) != 0) +
                       (((m4 >> 16) & 0xFFu) != 0) + (((m4 >> 24) & 0xFFu) != 0));
        atomicAdd(msum, mc);
    }
    __syncthreads();
    const int valid = N_P - *msum;

    // ---- phase B: segmented scan (position-wise insert) + shfl merge ----
    double kk[17];
    {
        const int qid = c15;                 // wave-local query 0..15
        const int s = g;                     // segment 0..3
        const int base = s << 8;
        const float4 me = spts[P0 + (w << 4) + qid];
        const float px = me.x, py = me.y, rp = me.z;

#pragma unroll
        for (int j = 0; j < 17; ++j) kk[j] = 0x1.0p60;

        int off = (2 * s) & 255;             // bank-skewed start
        float4 nq = spts[base + off];
        for (int i = 0; i < 256; ++i) {
            const float4 qc = nq;
            const int cur = base + off;
            off = (off + 1) & 255;
            nq = spts[base + off];           // broadcast prefetch
            float dot = __fadd_rn(__fmul_rn(px, qc.x), __fmul_rn(py, qc.y));
            float d   = __fadd_rn(__builtin_fmaf(-2.f, dot, rp), qc.z);
            unsigned int ud = __float_as_uint(d);
            ud ^= (unsigned int)((int)ud >> 31) | 0x80000000u;   // monotone map
            double x = __builtin_fma((double)ud, 1024.0, (double)cur); // exact
            // position-wise stable insert, chain depth 2 (maxes independent)
#pragma unroll
            for (int j = 16; j >= 1; --j)
                kk[j] = fmin(kk[j], fmax(kk[j - 1], x));
            kk[0] = fmin(kk[0], x);
        }
        // tree merge: xor 32 then 16. Senders insert +INF (exact no-op) so
        // their kk[] stays unmodified while receivers stream original keys.
#pragma unroll
        for (int r = 0; r < 2; ++r) {
            const int m = (r == 0) ? 32 : 16;
            const bool recv = (lane & m) == 0;
#pragma unroll
            for (int j = 0; j < 17; ++j) {
                double x = __shfl_xor(kk[j], m, 64);
                x = recv ? x : __builtin_inf();
#pragma unroll
                for (int jj = 16; jj >= 1; --jj)
                    kk[jj] = fmin(kk[jj], fmax(kk[jj - 1], x));
                kk[0] = fmin(kk[0], x);
            }
        }
        if (lane < 16) {
            const int row = (w << 4) + qid;
            // kk[0] = lex-min (d,idx) = self, dropped; kk[1..16] = neighbors
#pragma unroll
            for (int j = 1; j < 17; ++j) {
                double hi = __builtin_trunc(kk[j] * 0x1.0p-10);
                idx_lds[row][j - 1] = (int)(kk[j] - hi * 1024.0);
            }
        }
    }
    __syncthreads();   // all scans done; spts dead -> fbuf writable

    // ---- fold BN into weight fragments (per-lane registers) ----
    float tb0[4], tb1[4], tb2[4], tbs[4];
    f16x8 w0f[4], w1f[4][2], w2f[4][2];
    f16x4 wsf[4];
#pragma unroll
    for (int t = 0; t < 4; ++t) {
        const int o = t * 16 + c15;
        float s0 = g0[o] / sqrtf(v0[o] + 1e-5f);  tb0[t] = b0[o] - m0[o] * s0;
        float s1 = g1[o] / sqrtf(v1[o] + 1e-5f);  tb1[t] = b1[o] - m1[o] * s1;
        float s2 = g2[o] / sqrtf(v2[o] + 1e-5f);  tb2[t] = b2[o] - m2[o] * s2;
        float ss = gs[o] / sqrtf(vs[o] + 1e-5f);  tbs[t] = bs[o] - ms[o] * ss;
        const float* w0r = W0 + o * 32 + g * 8;
#pragma unroll
        for (int e = 0; e < 8; ++e) w0f[t][e] = (f16)(w0r[e] * s0);
        const float* w1r = W1 + o * 64 + g * 8;
        const float* w2r = W2 + o * 64 + g * 8;
#pragma unroll
        for (int ch = 0; ch < 2; ++ch)
#pragma unroll
            for (int e = 0; e < 8; ++e) {
                w1f[t][ch][e] = (f16)(w1r[ch * 32 + e] * s1);
                w2f[t][ch][e] = (f16)(w2r[ch * 32 + e] * s2);
            }
        const float* wsr = Ws + o * 16 + g * 4;
#pragma unroll
        for (int e = 0; e < 4; ++e) wsf[t][e] = (f16)(wsr[e] * ss);
    }

    // ---- per-point MLP: rows = 16 neighbors, cols = 64 channels ----
    for (int pp = 0; pp < 16; ++pp) {
        const int p = PB + pp;
        const int* ip = idx_lds[(w << 4) + pp];

        const int q = ip[c15];
        const int half = g & 1;
        const float* fcp = fB + p * C_IN + 2 + half * 8;
        float e0[8];
#pragma unroll
        for (int j = 0; j < 4; ++j) {
            float2 v = *(const float2*)(fcp + 2 * j);
            e0[2 * j] = v.x; e0[2 * j + 1] = v.y;
        }
        if (g >= 2) {
            const float* fqp = fB + q * C_IN + 2 + half * 8;
#pragma unroll
            for (int j = 0; j < 4; ++j) {
                float2 v = *(const float2*)(fqp + 2 * j);
                e0[2 * j] -= v.x; e0[2 * j + 1] -= v.y;
            }
        }
        f16x8 a0;
#pragma unroll
        for (int j = 0; j < 8; ++j) a0[j] = (f16)e0[j];

        // layer 0 (K=32), folded-BN bias in acc init
        f32x4 acc[4];
#pragma unroll
        for (int t = 0; t < 4; ++t) {
            acc[t] = (f32x4){tb0[t], tb0[t], tb0[t], tb0[t]};
            acc[t] = __builtin_amdgcn_mfma_f32_16x16x32_f16(a0, w0f[t], acc[t], 0, 0, 0);
        }
#pragma unroll
        for (int t = 0; t < 4; ++t)
#pragma unroll
            for (int r = 0; r < 4; ++r)
                hb[w][4 * g + r][t * 16 + c15] = (f16)fmaxf(acc[t][r], 0.f);

        // layer 1 (K=64)
        f16x8 a1a = *(const f16x8*)&hb[w][c15][g * 8];
        f16x8 a1b = *(const f16x8*)&hb[w][c15][32 + g * 8];
        f32x4 acc1[4];
#pragma unroll
        for (int t = 0; t < 4; ++t) {
            acc1[t] = (f32x4){tb1[t], tb1[t], tb1[t], tb1[t]};
            acc1[t] = __builtin_amdgcn_mfma_f32_16x16x32_f16(a1a, w1f[t][0], acc1[t], 0, 0, 0);
            acc1[t] = __builtin_amdgcn_mfma_f32_16x16x32_f16(a1b, w1f[t][1], acc1[t], 0, 0, 0);
        }
#pragma unroll
        for (int t = 0; t < 4; ++t)
#pragma unroll
            for (int r = 0; r < 4; ++r)
                hb[w][4 * g + r][t * 16 + c15] = (f16)fmaxf(acc1[t][r], 0.f);

        // layer 2 (K=64) + neighbor mask + k-mean
        f16x8 a2a = *(const f16x8*)&hb[w][c15][g * 8];
        f16x8 a2b = *(const f16x8*)&hb[w][c15][32 + g * 8];
        f32x4 acc2[4];
#pragma unroll
        for (int t = 0; t < 4; ++t) {
            acc2[t] = (f32x4){tb2[t], tb2[t], tb2[t], tb2[t]};
            acc2[t] = __builtin_amdgcn_mfma_f32_16x16x32_f16(a2a, w2f[t][0], acc2[t], 0, 0, 0);
            acc2[t] = __builtin_amdgcn_mfma_f32_16x16x32_f16(a2b, w2f[t][1], acc2[t], 0, 0, 0);
        }
        float ssum[4] = {0.f, 0.f, 0.f, 0.f};
        int cnt = 0;
#pragma unroll
        for (int r = 0; r < 4; ++r) {
            int qq = ip[4 * g + r];
            bool fl = (qq >= valid);
            cnt += fl ? 1 : 0;
#pragma unroll
            for (int t = 0; t < 4; ++t) {
                float v = fmaxf(acc2[t][r], 0.f);
                ssum[t] += fl ? 0.f : v;
            }
        }
#pragma unroll
        for (int t = 0; t < 4; ++t) {
            ssum[t] += __shfl_xor(ssum[t], 16);
            ssum[t] += __shfl_xor(ssum[t], 32);
        }
        cnt += __shfl_xor(cnt, 16);
        cnt += __shfl_xor(cnt, 32);
        float dn = fmaxf((float)(N_K - cnt), 1e-8f);
        if (g == 0) {
            int prow = (w << 4) + pp;
#pragma unroll
            for (int t = 0; t < 4; ++t)
                fbuf[prow][t * 16 + c15] = ssum[t] / dn;
        }
    }

    // ---- shortcut: sc = BN(Ws @ X) via 16x16x16 MFMA, rows = wave's 16 p ----
    {
        const float* xr = fB + (size_t)(PB + c15) * C_IN + 2 + g * 4;
        float2 xa = *(const float2*)(xr);
        float2 xb = *(const float2*)(xr + 2);
        f16x4 as;
        as[0] = (f16)xa.x; as[1] = (f16)xa.y; as[2] = (f16)xb.x; as[3] = (f16)xb.y;
        f32x4 sacc[4];
#pragma unroll
        for (int t = 0; t < 4; ++t) {
            sacc[t] = (f32x4){tbs[t], tbs[t], tbs[t], tbs[t]};
            sacc[t] = __builtin_amdgcn_mfma_f32_16x16x16f16(as, wsf[t], sacc[t], 0, 0, 0);
        }
        const unsigned char* mrow = mask + (size_t)n * N_P + P0;
#pragma unroll
        for (int r = 0; r < 4; ++r) {
            int pl = (w << 4) + 4 * g + r;
            bool mk = (mrow[pl] != 0);
#pragma unroll
            for (int t = 0; t < 4; ++t) {
                float a = fbuf[pl][t * 16 + c15];
                float sv = mk ? 0.f : sacc[t][r];
                fbuf[pl][t * 16 + c15] = fmaxf(a + sv, 0.f);
            }
        }
    }
    __syncthreads();

    // ---- transposed store: out[n][o][p], coalesced 256B per wave ----
    float* ob = out + (size_t)n * 64 * N_P + P0;
#pragma unroll
    for (int oo = 0; oo < 16; ++oo) {
        int o = (w << 4) + oo;
        ob[(size_t)o * N_P + lane] = fbuf[lane][o];
    }
}

extern "C" void kernel_launch(void* const* d_in, const int* in_sizes, int n_in,
                              void* d_out, int out_size, void* d_ws, size_t ws_size,
                              hipStream_t stream) {
    (void)in_sizes; (void)n_in; (void)out_size; (void)d_ws; (void)ws_size;
    const float* feat = (const float*)d_in[0];
    const unsigned char* mask = (const unsigned char*)d_in[1];
    const float* W0 = (const float*)d_in[2];
    const float* W1 = (const float*)d_in[3];
    const float* W2 = (const float*)d_in[4];
    const float* Ws = (const float*)d_in[5];
    const float* g0 = (const float*)d_in[6];
    const float* b0 = (const float*)d_in[7];
    const float* m0 = (const float*)d_in[8];
    const float* v0 = (const float*)d_in[9];
    const float* g1 = (const float*)d_in[10];
    const float* b1 = (const float*)d_in[11];
    const float* m1 = (const float*)d_in[12];
    const float* v1 = (const float*)d_in[13];
    const float* g2 = (const float*)d_in[14];
    const float* b2 = (const float*)d_in[15];
    const float* m2 = (const float*)d_in[16];
    const float* v2 = (const float*)d_in[17];
    const float* gs = (const float*)d_in[18];
    const float* bs = (const float*)d_in[19];
    const float* ms = (const float*)d_in[20];
    const float* vs = (const float*)d_in[21];
    float* out = (float*)d_out;

    fused_kernel<<<1024, 256, 0, stream>>>(feat, mask, W0, W1, W2, Ws,
                                           g0, b0, m0, v0, g1, b1, m1, v1,
                                           g2, b2, m2, v2, gs, bs, ms, vs,
                                           out);
}